// Round 3
// baseline (138.151 us; speedup 1.0000x reference)
//
#include <hip/hip_runtime.h>
#include <math.h>

// Problem constants
#define B_ 4
#define CIN_ 32
#define COUT_ 64
#define H_ 32
#define W_ 32

// ws layout:
//   feat: float4[B*CIN*H*W]  (cos p, sin p, cos 3p, sin 3p)          = 2 MB
//   coef: float [g:16][c:32][kl:9][j:4][8]   (o = g*4+j; 8 = A1..4,B1..4)
#define FEAT_ELEMS (B_ * CIN_ * H_ * W_)      // 131072
#define COEF_OFF_BYTES (FEAT_ELEMS * 16)      // feat is float4
#define NCOEF (CIN_ * COUT_ * 9)              // 18432

__global__ __launch_bounds__(256) void ring_prep(
    const float* __restrict__ x, const float* __restrict__ probe,
    const float* __restrict__ outw, float* __restrict__ feat,
    float* __restrict__ coef) {
  int i = blockIdx.x * 256 + threadIdx.x;
  if (i < FEAT_ELEMS) {
    float p = x[i];
    float s1, c1;
    __sincosf(p, &s1, &c1);
    float c3 = c1 * fmaf(4.0f * c1, c1, -3.0f);
    float s3 = s1 * fmaf(-4.0f * s1, s1, 3.0f);
    float4 v;
    v.x = c1; v.y = s1; v.z = c3; v.w = s3;
    ((float4*)feat)[i] = v;
  }
  if (i < NCOEF) {
    // input flat idx: ((c*COUT + o)*3 + k)*3 + l
    int kl = i % 9;
    int co = i / 9;
    int o = co % COUT_;
    int c = co / COUT_;
    float th = probe[i];
    float wv = outw[i];
    float sth, cth, sw, cw;
    __sincosf(th, &sth, &cth);
    __sincosf(wv, &sw, &cw);
    float c3th = cth * fmaf(4.0f * cth, cth, -3.0f);
    float s3th = sth * fmaf(-4.0f * sth, sth, 3.0f);
    int g = o >> 2, j = o & 3;
    float* dst = coef + ((((size_t)g * CIN_ + c) * 9 + kl) * 4 + j) * 8;
    dst[0] = 0.75f * cw * cth;
    dst[1] = 0.75f * cw * sth;
    dst[2] = 0.25f * cw * c3th;
    dst[3] = 0.25f * cw * s3th;
    dst[4] = 0.75f * sw * cth;
    dst[5] = 0.75f * sw * sth;
    dst[6] = 0.25f * sw * c3th;
    dst[7] = 0.25f * sw * s3th;
  }
}

// Block: 64 pixels (2 rows x 32 w) x 16 outputs. 4 waves; each wave owns 4
// outputs (wave-uniform -> coef via scalar loads), all waves share one
// feature tile in LDS: 4 rows (2+halo) x 32 c x 34 cols x float4 = 69632 B.
#define SF_ELEMS (CIN_ * 4 * 34)

__global__ __launch_bounds__(256) void ring_main(
    const float4* __restrict__ feat, const float* __restrict__ coef,
    float* __restrict__ out) {
  __shared__ float4 sfeat[SF_ELEMS];   // [c][r:4][col:34]

  int blk = blockIdx.x;                // ((b*16 + rp)*4 + og)
  int og = blk & 3;
  int rp = (blk >> 2) & 15;
  int b = blk >> 6;
  int tid = threadIdx.x;

  // ---- stage feature tile (rows 2rp-1 .. 2rp+2, padded) ----
  for (int e = tid; e < SF_ELEMS; e += 256) {
    int c = e / 136;
    int rem = e - c * 136;
    int r = rem / 34;
    int col = rem - r * 34;
    int hs = rp * 2 - 1 + r;
    int ws = col - 1;
    float4 v = make_float4(1.0f, 0.0f, 1.0f, 0.0f);  // p = 0 pad
    if ((unsigned)hs < (unsigned)H_ && (unsigned)ws < (unsigned)W_)
      v = feat[((b * CIN_ + c) * H_ + hs) * W_ + ws];
    sfeat[e] = v;
  }
  __syncthreads();

  int wv = __builtin_amdgcn_readfirstlane(tid >> 6);  // wave id, scalar
  int lane = tid & 63;
  int r = lane >> 5;                   // 0..1 : row within pair
  int w = lane & 31;                   // 0..31
  int g = og * 4 + wv;                 // output quad id, scalar
  const float* cf_base = coef + (size_t)g * (CIN_ * 9 * 32);

  float ax[4] = {0.f, 0.f, 0.f, 0.f};
  float ay[4] = {0.f, 0.f, 0.f, 0.f};

  for (int c = 0; c < CIN_; ++c) {
    const float4* srow = &sfeat[c * 136 + r * 34 + w];
    const float* cfc = cf_base + c * (9 * 32);
#pragma unroll
    for (int k = 0; k < 3; ++k) {
#pragma unroll
      for (int l = 0; l < 3; ++l) {
        float4 f = srow[k * 34 + l];
        const float* cf = cfc + (k * 3 + l) * 32;  // 32 scalar floats
#pragma unroll
        for (int j = 0; j < 4; ++j) {
          ax[j] = fmaf(cf[j * 8 + 0], f.x, ax[j]);
          ax[j] = fmaf(cf[j * 8 + 1], f.y, ax[j]);
          ax[j] = fmaf(cf[j * 8 + 2], f.z, ax[j]);
          ax[j] = fmaf(cf[j * 8 + 3], f.w, ax[j]);
          ay[j] = fmaf(cf[j * 8 + 4], f.x, ay[j]);
          ay[j] = fmaf(cf[j * 8 + 5], f.y, ay[j]);
          ay[j] = fmaf(cf[j * 8 + 6], f.z, ay[j]);
          ay[j] = fmaf(cf[j * 8 + 7], f.w, ay[j]);
        }
      }
    }
  }

  int h = rp * 2 + r;
#pragma unroll
  for (int j = 0; j < 4; ++j) {
    int o = g * 4 + j;
    out[((b * COUT_ + o) * H_ + h) * W_ + w] = atan2f(ay[j], ax[j]);
  }
}

extern "C" void kernel_launch(void* const* d_in, const int* in_sizes, int n_in,
                              void* d_out, int out_size, void* d_ws, size_t ws_size,
                              hipStream_t stream) {
  const float* x = (const float*)d_in[0];
  const float* probe = (const float*)d_in[1];
  const float* outw = (const float*)d_in[2];
  float* feat = (float*)d_ws;
  float* coef = (float*)((char*)d_ws + COEF_OFF_BYTES);
  float* out = (float*)d_out;

  ring_prep<<<FEAT_ELEMS / 256, 256, 0, stream>>>(x, probe, outw, feat, coef);
  ring_main<<<B_ * 16 * 4, 256, 0, stream>>>((const float4*)feat, coef, out);
}